// Round 12
// baseline (311.236 us; speedup 1.0000x reference)
//
#include <hip/hip_runtime.h>
#include <hip/hip_fp16.h>
#include <math.h>

typedef _Float16 h2_t __attribute__((ext_vector_type(2)));
typedef _Float16 h4_t __attribute__((ext_vector_type(4)));
typedef _Float16 h8_t __attribute__((ext_vector_type(8)));
typedef float f4_t __attribute__((ext_vector_type(4)));
typedef float f8_t __attribute__((ext_vector_type(8)));

#define STREAM_BLOCKS 2048

__device__ inline h8_t load8f_to_h8(const float* p) {
    float4 a = *(const float4*)p;
    float4 b = *(const float4*)(p + 4);
    h8_t r;
    r[0] = (_Float16)a.x; r[1] = (_Float16)a.y; r[2] = (_Float16)a.z; r[3] = (_Float16)a.w;
    r[4] = (_Float16)b.x; r[5] = (_Float16)b.y; r[6] = (_Float16)b.z; r[7] = (_Float16)b.w;
    return r;
}

__device__ inline h4_t load4f_to_h4(const float* p) {
    float4 a = *(const float4*)p;
    h4_t r;
    r[0] = (_Float16)a.x; r[1] = (_Float16)a.y; r[2] = (_Float16)a.z; r[3] = (_Float16)a.w;
    return r;
}

__device__ inline float dot8h(h8_t a, h8_t b, float s) {
    s = __builtin_amdgcn_fdot2(__builtin_shufflevector(a, a, 0, 1),
                               __builtin_shufflevector(b, b, 0, 1), s, false);
    s = __builtin_amdgcn_fdot2(__builtin_shufflevector(a, a, 2, 3),
                               __builtin_shufflevector(b, b, 2, 3), s, false);
    s = __builtin_amdgcn_fdot2(__builtin_shufflevector(a, a, 4, 5),
                               __builtin_shufflevector(b, b, 4, 5), s, false);
    s = __builtin_amdgcn_fdot2(__builtin_shufflevector(a, a, 6, 7),
                               __builtin_shufflevector(b, b, 6, 7), s, false);
    return s;
}

__device__ inline float dot4h(h4_t a, h4_t b, float s) {
    s = __builtin_amdgcn_fdot2(__builtin_shufflevector(a, a, 0, 1),
                               __builtin_shufflevector(b, b, 0, 1), s, false);
    s = __builtin_amdgcn_fdot2(__builtin_shufflevector(a, a, 2, 3),
                               __builtin_shufflevector(b, b, 2, 3), s, false);
    return s;
}

__device__ inline float elu1(float v) { return v > 0.f ? v : __expf(v) - 1.f; }

// ---- k_pre: x->fp16, eattr partials, edge count+rank, flags zero, W pack -
// Blocks 0..2047: streaming (cnt pre-zeroed by memset). Blocks 2048+: pack
// weights into MFMA A-fragment layout: group g holds
// W[s*32 + quad*8 + j][t*16 + m], g=(t*4+s)*64+lane, m=lane&15, quad=lane>>4.

__global__ __launch_bounds__(256) void k_pre(const float* __restrict__ eattr,
                                             const int* __restrict__ ei, int E,
                                             int* __restrict__ cnt, int N, int NB,
                                             float* __restrict__ part,
                                             unsigned* __restrict__ flags,
                                             const float* __restrict__ x,
                                             _Float16* __restrict__ xh,
                                             int* __restrict__ rank,
                                             const float* __restrict__ w1l,
                                             const float* __restrict__ w1r,
                                             const float* __restrict__ w2l,
                                             const float* __restrict__ w2r,
                                             _Float16* __restrict__ p1l,
                                             _Float16* __restrict__ p1r,
                                             _Float16* __restrict__ p2l,
                                             _Float16* __restrict__ p2r) {
    if (blockIdx.x >= STREAM_BLOCKS) {
        int g = (blockIdx.x - STREAM_BLOCKS) * 256 + threadIdx.x;
        const float* W;
        _Float16* P;
        int M, lg;
        if (g < 2048)      { W = w1l; P = p1l; M = 128; lg = g; }
        else if (g < 4096) { W = w1r; P = p1r; M = 128; lg = g - 2048; }
        else if (g < 5120) { W = w2l; P = p2l; M = 64;  lg = g - 4096; }
        else if (g < 6144) { W = w2r; P = p2r; M = 64;  lg = g - 5120; }
        else return;
        int lane = lg & 63;
        int s = (lg >> 6) & 3;
        int t = lg >> 8;
        int m = lane & 15, quad = lane >> 4;
        h8_t v;
#pragma unroll
        for (int j = 0; j < 8; ++j)
            v[j] = (_Float16)W[(size_t)(s * 32 + quad * 8 + j) * M + t * 16 + m];
        *(h8_t*)(P + (size_t)lg * 8) = v;
        return;
    }
    int t = blockIdx.x * 256 + threadIdx.x;
    const int stride = STREAM_BLOCKS * 256;
    // zero lookback flags
    for (int i = t; i < NB; i += stride) flags[i] = 0u;
    // x -> fp16
    int nchunk = (N * 128) >> 3;
    for (int i = t; i < nchunk; i += stride) {
        h8_t v = load8f_to_h8(x + (size_t)i * 8);
        *(h8_t*)(xh + (size_t)i * 8) = v;
    }
    // per-dst count + arrival rank (<=2 independent atomics per thread)
    for (int e = t; e < E; e += stride) rank[e] = atomicAdd(&cnt[ei[E + e]], 1);
    // edge_attr partial sums
    float s = 0.f;
    for (int i = t; i < E; i += stride) s += eattr[i];
    __shared__ float sd[4];
    for (int o = 1; o < 64; o <<= 1) s += __shfl_xor(s, o, 64);
    if ((threadIdx.x & 63) == 0) sd[threadIdx.x >> 6] = s;
    __syncthreads();
    if (threadIdx.x == 0) part[blockIdx.x] = sd[0] + sd[1] + sd[2] + sd[3];
}

// ---- k_scan: single-kernel exclusive scan of (cnt+1) via decoupled
// lookback + off[] + self-loop edge records. NB=196 blocks with
// __launch_bounds__(256,1) -> all co-resident on 256 CUs (lookback safe).

__global__ __launch_bounds__(256, 1) void k_scan(const int* __restrict__ cnt, int N,
                                                 unsigned* __restrict__ flags,
                                                 const float* __restrict__ part, float invE,
                                                 int* __restrict__ off,
                                                 unsigned* __restrict__ edges) {
    __shared__ int tmp[256];
    __shared__ int sbase;
    __shared__ float smean;
    int tx = threadIdx.x;
    int b = blockIdx.x;
    int i = b * 256 + tx;

    // block-local mean(edge_attr) from the 2048 partials
    {
        float s = 0.f;
#pragma unroll
        for (int k = 0; k < STREAM_BLOCKS / 256; ++k) s += part[tx + k * 256];
        for (int o = 1; o < 64; o <<= 1) s += __shfl_xor(s, o, 64);
        __shared__ float sd[4];
        if ((tx & 63) == 0) sd[tx >> 6] = s;
        __syncthreads();
        if (tx == 0) smean = (sd[0] + sd[1] + sd[2] + sd[3]) * invE;
    }

    int v = (i < N) ? cnt[i] + 1 : 0;
    tmp[tx] = v;
    __syncthreads();
    for (int o = 1; o < 256; o <<= 1) {
        int t = (tx >= o) ? tmp[tx - o] : 0;
        __syncthreads();
        tmp[tx] += t;
        __syncthreads();
    }
    int T = tmp[255];
    if (tx == 0) {
        if (b == 0) {
            atomicExch(&flags[0], (2u << 30) | (unsigned)T);
            sbase = 0;
        } else {
            atomicExch(&flags[b], (1u << 30) | (unsigned)T);
            int running = 0;
            int j = b - 1;
            while (true) {
                unsigned f = atomicAdd(&flags[j], 0u);
                unsigned st = f >> 30;
                if (st == 0u) continue;
                running += (int)(f & 0x3FFFFFFFu);
                if (st == 2u) break;
                --j;
            }
            atomicExch(&flags[b], (2u << 30) | (unsigned)(running + T));
            sbase = running;
        }
    }
    __syncthreads();
    if (i < N) {
        int o = sbase + tmp[tx] - v;
        off[i] = o;
        unsigned qv = (unsigned)__float2int_rn(smean * 255.f);
        edges[o] = (unsigned)i | (qv << 24);  // self-loop record in slot 0
    }
}

// atomic-free scatter: pos = off[dst] + 1 + rank[e]
__global__ __launch_bounds__(256) void k_fill(const int* __restrict__ ei,
                                              const float* __restrict__ eattr,
                                              const int* __restrict__ rank,
                                              const int* __restrict__ off, int E,
                                              unsigned* __restrict__ edges) {
    int e = blockIdx.x * 256 + threadIdx.x;
    if (e >= E) return;
    int d = ei[E + e];
    int pos = off[d] + 1 + rank[e];
    unsigned qv = (unsigned)__float2int_rn(eattr[e] * 255.f);
    edges[pos] = (unsigned)ei[e] | (qv << 24);
}

// ---- MFMA GEMM (verified) ------------------------------------------------

template <int NT>
__global__ __launch_bounds__(256) void k_mm(const _Float16* __restrict__ X,
                                            const _Float16* __restrict__ P0,
                                            const float* __restrict__ b0,
                                            _Float16* __restrict__ Y0,
                                            const _Float16* __restrict__ P1,
                                            const float* __restrict__ b1,
                                            _Float16* __restrict__ Y1, int N) {
    int wid = blockIdx.x * 4 + (threadIdx.x >> 6);
    int rowbase = wid * 16;
    if (rowbase >= N) return;
    int lane = threadIdx.x & 63;
    int nrow = lane & 15;
    int quad = lane >> 4;
    const int M = NT * 16;

    f4_t acc[2][NT];
#pragma unroll
    for (int w = 0; w < 2; ++w)
#pragma unroll
        for (int t = 0; t < NT; ++t) acc[w][t] = (f4_t){0.f, 0.f, 0.f, 0.f};

    const _Float16* xp = X + (size_t)(rowbase + nrow) * 128 + quad * 8;
#pragma unroll
    for (int s = 0; s < 4; ++s) {
        h8_t b = *(const h8_t*)(xp + s * 32);
#pragma unroll
        for (int t = 0; t < NT; ++t) {
            h8_t a0 = *(const h8_t*)(P0 + (((size_t)t * 4 + s) * 64 + lane) * 8);
            acc[0][t] = __builtin_amdgcn_mfma_f32_16x16x32_f16(a0, b, acc[0][t], 0, 0, 0);
        }
#pragma unroll
        for (int t = 0; t < NT; ++t) {
            h8_t a1 = *(const h8_t*)(P1 + (((size_t)t * 4 + s) * 64 + lane) * 8);
            acc[1][t] = __builtin_amdgcn_mfma_f32_16x16x32_f16(a1, b, acc[1][t], 0, 0, 0);
        }
    }
    int row = rowbase + nrow;
#pragma unroll
    for (int w = 0; w < 2; ++w) {
        _Float16* Y = w ? Y1 : Y0;
        const float* bias = w ? b1 : b0;
#pragma unroll
        for (int t = 0; t < NT; ++t) {
            float4 bv = *(const float4*)(bias + t * 16 + quad * 4);
            h4_t o;
            o[0] = (_Float16)(acc[w][t][0] + bv.x);
            o[1] = (_Float16)(acc[w][t][1] + bv.y);
            o[2] = (_Float16)(acc[w][t][2] + bv.z);
            o[3] = (_Float16)(acc[w][t][3] + bv.w);
            *(h4_t*)(Y + (size_t)row * M + t * 16 + quad * 4) = o;
        }
    }
}

// ---- GATv2 layer 1 node pass (parked at ~51 us gather plateau) -----------

__global__ __launch_bounds__(256) void k_node1(const _Float16* __restrict__ xlh,
                                               const _Float16* __restrict__ xrh,
                                               const int* __restrict__ off,
                                               const int* __restrict__ cnt,
                                               const unsigned* __restrict__ edges,
                                               const float* __restrict__ we,
                                               const float* __restrict__ att,
                                               const float* __restrict__ bias,
                                               _Float16* __restrict__ h, int N) {
    int lane = threadIdx.x & 63;
    int node = blockIdx.x * 4 + (threadIdx.x >> 6);
    if (node >= N) return;
    int g = lane >> 4;
    int q = lane & 15;
    int c0 = q * 8;

    h8_t xrv = *(const h8_t*)(xrh + (size_t)node * 128 + c0);
    h8_t wev = load8f_to_h8(we + c0);
    h8_t atv = load8f_to_h8(att + c0);
    int start = off[node];
    int deg1 = cnt[node] + 1;
    int last = deg1 - 1;

    float l = 0.f;
    f8_t acc = {0.f, 0.f, 0.f, 0.f, 0.f, 0.f, 0.f, 0.f};
    for (int i = 0; i < deg1; i += 16) {
        int s0 = i + g, s1 = i + 4 + g, s2 = i + 8 + g, s3 = i + 12 + g;
        unsigned p0 = edges[start + min(s0, last)];
        unsigned p1 = edges[start + min(s1, last)];
        unsigned p2 = edges[start + min(s2, last)];
        unsigned p3 = edges[start + min(s3, last)];
        h8_t x0 = *(const h8_t*)(xlh + (size_t)(p0 & 0x00FFFFFFu) * 128 + c0);
        h8_t x1 = *(const h8_t*)(xlh + (size_t)(p1 & 0x00FFFFFFu) * 128 + c0);
        h8_t x2 = *(const h8_t*)(xlh + (size_t)(p2 & 0x00FFFFFFu) * 128 + c0);
        h8_t x3 = *(const h8_t*)(xlh + (size_t)(p3 & 0x00FFFFFFu) * 128 + c0);
        float e0 = (float)(p0 >> 24) * (1.f / 255.f);
        float e1 = (float)(p1 >> 24) * (1.f / 255.f);
        float e2 = (float)(p2 >> 24) * (1.f / 255.f);
        float e3 = (float)(p3 >> 24) * (1.f / 255.f);
        h8_t z0 = x0 + xrv + wev * (_Float16)e0;
        z0 = __builtin_elementwise_max(z0, z0 * (_Float16)0.2f);
        float sc0 = dot8h(z0, atv, 0.f);
        h8_t z1 = x1 + xrv + wev * (_Float16)e1;
        z1 = __builtin_elementwise_max(z1, z1 * (_Float16)0.2f);
        float sc1 = dot8h(z1, atv, 0.f);
        h8_t z2 = x2 + xrv + wev * (_Float16)e2;
        z2 = __builtin_elementwise_max(z2, z2 * (_Float16)0.2f);
        float sc2 = dot8h(z2, atv, 0.f);
        h8_t z3 = x3 + xrv + wev * (_Float16)e3;
        z3 = __builtin_elementwise_max(z3, z3 * (_Float16)0.2f);
        float sc3 = dot8h(z3, atv, 0.f);
        sc0 += __shfl_xor(sc0, 1, 64); sc0 += __shfl_xor(sc0, 2, 64);
        sc1 += __shfl_xor(sc1, 1, 64); sc1 += __shfl_xor(sc1, 2, 64);
        sc2 += __shfl_xor(sc2, 1, 64); sc2 += __shfl_xor(sc2, 2, 64);
        sc3 += __shfl_xor(sc3, 1, 64); sc3 += __shfl_xor(sc3, 2, 64);
        float pA = (s0 < deg1) ? __expf(fminf(sc0, 60.f)) : 0.f;
        float pB = (s1 < deg1) ? __expf(fminf(sc1, 60.f)) : 0.f;
        float pC = (s2 < deg1) ? __expf(fminf(sc2, 60.f)) : 0.f;
        float pD = (s3 < deg1) ? __expf(fminf(sc3, 60.f)) : 0.f;
        l += (pA + pB) + (pC + pD);
#pragma unroll
        for (int k = 0; k < 8; ++k)
            acc[k] = fmaf(pA, (float)x0[k],
                     fmaf(pB, (float)x1[k], fmaf(pC, (float)x2[k], fmaf(pD, (float)x3[k], acc[k]))));
    }
#pragma unroll
    for (int k = 0; k < 8; ++k) {
        acc[k] += __shfl_xor(acc[k], 16, 64);
        acc[k] += __shfl_xor(acc[k], 32, 64);
    }
    l += __shfl_xor(l, 16, 64);
    l += __shfl_xor(l, 32, 64);
    if (g == 0) {
        float inv = 1.f / l;
        float4 b0 = *(const float4*)(bias + c0);
        float4 b1 = *(const float4*)(bias + c0 + 4);
        float bb[8] = {b0.x, b0.y, b0.z, b0.w, b1.x, b1.y, b1.z, b1.w};
        h8_t o;
#pragma unroll
        for (int k = 0; k < 8; ++k) o[k] = (_Float16)elu1(fmaf(acc[k], inv, bb[k]));
        *(h8_t*)(h + (size_t)node * 128 + c0) = o;
    }
}

// ---- GATv2 layer 2 node pass + fused classifier --------------------------

__global__ __launch_bounds__(256) void k_node2(const _Float16* __restrict__ xlh,
                                               const _Float16* __restrict__ xrh,
                                               const int* __restrict__ off,
                                               const int* __restrict__ cnt,
                                               const unsigned* __restrict__ edges,
                                               const float* __restrict__ we,
                                               const float* __restrict__ att,
                                               const float* __restrict__ bias,
                                               const float* __restrict__ wc,
                                               const float* __restrict__ bc,
                                               float* __restrict__ out, int N) {
    __shared__ float h2s[16][33];
    int lane = threadIdx.x & 63;
    int sub = lane >> 4;
    int r = lane & 15;
    int nloc = (threadIdx.x >> 6) * 4 + sub;
    int node = blockIdx.x * 16 + nloc;
    int c0 = r * 4;

    if (node < N) {
        h4_t xrv = *(const h4_t*)(xrh + (size_t)node * 64 + c0);
        h4_t wev = load4f_to_h4(we + c0);
        h4_t atv = load4f_to_h4(att + c0);
        int start = off[node];
        int deg1 = cnt[node] + 1;
        int last = deg1 - 1;

        float l = 0.f;
        float acc[4] = {0.f, 0.f, 0.f, 0.f};
        for (int i = 0; i < deg1; i += 4) {
            unsigned p[4];
            h4_t xv[4];
#pragma unroll
            for (int j = 0; j < 4; ++j) p[j] = edges[start + min(i + j, last)];
#pragma unroll
            for (int j = 0; j < 4; ++j)
                xv[j] = *(const h4_t*)(xlh + (size_t)(p[j] & 0x00FFFFFFu) * 64 + c0);
#pragma unroll
            for (int j = 0; j < 4; ++j) {
                float ea = (float)(p[j] >> 24) * (1.f / 255.f);
                h4_t z = xv[j] + xrv + wev * (_Float16)ea;
                z = __builtin_elementwise_max(z, z * (_Float16)0.2f);
                float sc = dot4h(z, atv, 0.f);
                sc += __shfl_xor(sc, 1, 64);
                sc += __shfl_xor(sc, 2, 64);
                sc += __shfl_xor(sc, 4, 64);
                float pp = (i + j < deg1) ? __expf(fminf(sc, 60.f)) : 0.f;
                l += pp;
#pragma unroll
                for (int k = 0; k < 4; ++k) acc[k] = fmaf(pp, (float)xv[j][k], acc[k]);
            }
        }
        float inv = 1.f / l;
#pragma unroll
        for (int k = 0; k < 4; ++k) {
            float norm = acc[k] * inv;
            float other = __shfl_xor(norm, 8, 64);
            float v = 0.5f * (norm + other);
            if (r < 8) h2s[nloc][c0 + k] = elu1(v + bias[c0 + k]);
        }
    }
    __syncthreads();
    int t = threadIdx.x;
    if (t < 128) {
        int n = t >> 3, j = t & 7;
        int gnode = blockIdx.x * 16 + n;
        if (gnode < N) {
            float acc = bc[j];
#pragma unroll 8
            for (int d = 0; d < 32; ++d) acc = fmaf(h2s[n][d], wc[d * 8 + j], acc);
            out[(size_t)gnode * 8 + j] = acc;
        }
    }
}

// ---- launch --------------------------------------------------------------

extern "C" void kernel_launch(void* const* d_in, const int* in_sizes, int n_in,
                              void* d_out, int out_size, void* d_ws, size_t ws_size,
                              hipStream_t stream) {
    const float* x     = (const float*)d_in[0];
    const int*   ei    = (const int*)d_in[1];
    const float* eattr = (const float*)d_in[2];
    const float* w1l = (const float*)d_in[3];
    const float* b1l = (const float*)d_in[4];
    const float* w1r = (const float*)d_in[5];
    const float* b1r = (const float*)d_in[6];
    const float* w1e = (const float*)d_in[7];
    const float* att1 = (const float*)d_in[8];
    const float* bias1 = (const float*)d_in[9];
    const float* w2l = (const float*)d_in[10];
    const float* b2l = (const float*)d_in[11];
    const float* w2r = (const float*)d_in[12];
    const float* b2r = (const float*)d_in[13];
    const float* w2e = (const float*)d_in[14];
    const float* att2 = (const float*)d_in[15];
    const float* bias2 = (const float*)d_in[16];
    const float* wc = (const float*)d_in[17];
    const float* bc = (const float*)d_in[18];
    float* out = (float*)d_out;

    const int N = in_sizes[0] / 128;
    const int E = in_sizes[2];
    const int tot = E + N;

    char* ws = (char*)d_ws;
    size_t o = 0;
    auto alloc = [&](size_t bytes) -> void* {
        void* p = ws + o;
        o += (bytes + 255) & ~(size_t)255;
        return p;
    };
    _Float16* xh   = (_Float16*)alloc((size_t)N * 128 * 2);
    _Float16* xl1h = (_Float16*)alloc((size_t)N * 128 * 2);
    _Float16* xr1h = (_Float16*)alloc((size_t)N * 128 * 2);
    _Float16* h1h  = (_Float16*)alloc((size_t)N * 128 * 2);
    _Float16* xl2h = (_Float16*)alloc((size_t)N * 64 * 2);
    _Float16* xr2h = (_Float16*)alloc((size_t)N * 64 * 2);
    _Float16* p1l  = (_Float16*)alloc(128 * 128 * 2);
    _Float16* p1r  = (_Float16*)alloc(128 * 128 * 2);
    _Float16* p2l  = (_Float16*)alloc(128 * 64 * 2);
    _Float16* p2r  = (_Float16*)alloc(128 * 64 * 2);
    int* cnt    = (int*)alloc((size_t)N * 4);
    int* offb   = (int*)alloc((size_t)N * 4);
    int* rank   = (int*)alloc((size_t)E * 4);
    unsigned* flags = (unsigned*)alloc(1024 * 4);
    float* part = (float*)alloc(STREAM_BLOCKS * 4);
    unsigned* edges = (unsigned*)alloc((size_t)tot * 4);

    const int NB = (N + 255) / 256;
    const int NW = (N + 63) / 64;

    hipMemsetAsync(cnt, 0, (size_t)N * 4, stream);
    k_pre<<<STREAM_BLOCKS + 24, 256, 0, stream>>>(eattr, ei, E, cnt, N, NB, part, flags,
                                                  x, xh, rank, w1l, w1r, w2l, w2r,
                                                  p1l, p1r, p2l, p2r);
    k_scan<<<NB, 256, 0, stream>>>(cnt, N, flags, part, 1.0f / (float)E, offb, edges);
    k_fill<<<(E + 255) / 256, 256, 0, stream>>>(ei, eattr, rank, offb, E, edges);

    k_mm<8><<<NW, 256, 0, stream>>>(xh, p1l, b1l, xl1h, p1r, b1r, xr1h, N);
    k_node1<<<(N + 3) / 4, 256, 0, stream>>>(xl1h, xr1h, offb, cnt, edges, w1e, att1, bias1,
                                             h1h, N);
    k_mm<4><<<NW, 256, 0, stream>>>(h1h, p2l, b2l, xl2h, p2r, b2r, xr2h, N);
    k_node2<<<(N + 15) / 16, 256, 0, stream>>>(xl2h, xr2h, offb, cnt, edges, w2e, att2, bias2,
                                               wc, bc, out, N);
}